// Round 10
// baseline (522.948 us; speedup 1.0000x reference)
//
#include <hip/hip_runtime.h>
#include <hip/hip_fp16.h>
#include <hip/hip_fp8.h>
#include <math.h>

#define CUTOFF 5.0f
#define H 64
#define FIN 16
#define NLAYERS 3
#define LUTN 2048          // intervals; table has LUTN+1 entries
#define LUTSTRIDE 2052     // padded per-layer stride
#define ASTRIDE 72         // LDS row stride in halves (pad 64->72: <=2-way conflicts)
#define LUTB 9             // lut blocks per layer (9*256 >= 2049)

// 1/sqrt(1 + 1e-3)  (BN inference, moving mean 0 / var 1)
#define BN_INV 0.999500374750f

typedef _Float16 h8 __attribute__((ext_vector_type(8)));
typedef float f32x4 __attribute__((ext_vector_type(4)));

__device__ __forceinline__ float softplus_f(float x) {
    return fmaxf(x, 0.f) + __logf(1.f + __expf(-fabsf(x)));
}

// ---- K1: mega setup. Block roles by blockIdx range:
//   [0, nbE)            embed 4 nodes/block -> hb fp16 + hq fp8; zero cnt; b0 zeros gsum/done
//   [nbE, nbE+27)       LUT: per-block inline wsum/bsum (LDS), 256 entries/block
//   [nbE+27, nbE+39)    weight swizzle Wsw + b2p
__global__ __launch_bounds__(256)
void k_setup(const float* __restrict__ x, const float* __restrict__ emb_W,
             const float* __restrict__ emb_b, __half* __restrict__ hb,
             unsigned char* __restrict__ hq,
             const float* __restrict__ fW1, const float* __restrict__ fb1,
             const float* __restrict__ fW2, const float* __restrict__ fb2,
             const float* __restrict__ iW1, const float* __restrict__ iW2,
             const float* __restrict__ bn_g, const float* __restrict__ bn_b,
             const float* __restrict__ ib2, h8* __restrict__ Wsw,
             float* __restrict__ b2p, float* __restrict__ lut,
             int* __restrict__ cnt, float* __restrict__ gsum,
             int* __restrict__ done, int N) {
    __shared__ float swsum[64];
    __shared__ float sbsum;
    int b = blockIdx.x;
    int t = threadIdx.x;
    int nbE = (N + 3) / 4;
    if (b < nbE) {
        // zero bookkeeping
        int ci = b * 4 + t;
        if (t < 4 && ci < N) cnt[ci] = 0;
        if (b == 0) {
            if (t < 64) gsum[t] = 0.f;
            if (t == 64) *done = 0;
        }
        // embed
        int lane = t & 63;
        int w = t >> 6;
        int node = b * 4 + w;
        if (node < N) {
            float acc = emb_b[lane];
#pragma unroll
            for (int k = 0; k < FIN; k++) acc += x[node * FIN + k] * emb_W[k * H + lane];
            size_t idx = (size_t)node * H + lane;
            hb[idx] = __float2half(acc);
            __hip_fp8_e4m3 q(acc);
            hq[idx] = q.__x;
        }
    } else if (b < nbE + NLAYERS * LUTB) {
        int lb = b - nbE;
        int l = lb / LUTB, part = lb % LUTB;
        if (t < 64) {
            float s = 0.f;
            for (int j = 0; j < H; j++) s += fW2[l * H * H + t * H + j];
            swsum[t] = s;
        }
        if (t == 64) {
            float s = 0.f;
            for (int j = 0; j < H; j++) s += fb2[l * H + j];
            sbsum = s;
        }
        __syncthreads();
        int i = part * 256 + t;
        if (i <= LUTN) {
            float d = (float)i * (CUTOFF / (float)LUTN);
            float scaled = d * (2.0f / CUTOFF) - 1.0f;
            float cut = 0.5f * (__cosf(d * (3.14159265358979f / CUTOFF)) + 1.0f);
            if (d > CUTOFF) cut = 0.f;
            float s = 0.f;
            for (int hh = 0; hh < H; hh++) {
                int wi = l * H + hh;
                s += tanhf(scaled * fW1[wi] + fb1[wi]) * swsum[hh];
            }
            lut[l * LUTSTRIDE + i] = cut * (s + sbsum);
        }
    } else {
        int tid = (b - nbE - NLAYERS * LUTB) * 256 + t;
        if (tid < NLAYERS * H)
            b2p[tid] = ib2[tid] * BN_INV * bn_g[tid] + bn_b[tid];
        if (tid < NLAYERS * 2 * 8 * 64) {
            int lane = tid & 63;
            int frag = (tid >> 6) & 7;
            int mat  = (tid >> 9) & 1;
            int l    = tid >> 10;
            int kt = frag >> 2, nt = frag & 3;
            int n = nt * 16 + (lane & 15);
            int k0 = kt * 32 + (lane >> 4) * 8;
            const float* W = (mat ? iW2 : iW1) + l * H * H;
            float scale = mat ? BN_INV * bn_g[l * H + n] : 1.0f;
            h8 v;
#pragma unroll
            for (int j = 0; j < 8; j++) v[j] = (_Float16)(W[(k0 + j) * H + n] * scale);
            Wsw[tid] = v;
        }
    }
}

// Histogram of destination rows; atomic return value IS the within-row rank.
__global__ __launch_bounds__(256)
void k_hist(const int* __restrict__ ei, int* __restrict__ cnt,
            unsigned char* __restrict__ rank8, int E) {
    int e = blockIdx.x * 256 + threadIdx.x;
    if (e < E) {
        int r = atomicAdd(&cnt[ei[e]], 1);
        rank8[e] = (unsigned char)r;
    }
}

// scan stage 1: per-256-block sums of cnt
__global__ void k_scan1(const int* __restrict__ cnt, int* __restrict__ bsums, int N) {
    __shared__ int sd[256];
    int i = blockIdx.x * 256 + threadIdx.x;
    sd[threadIdx.x] = (i < N) ? cnt[i] : 0;
    __syncthreads();
    for (int off = 128; off > 0; off >>= 1) {
        if (threadIdx.x < off) sd[threadIdx.x] += sd[threadIdx.x + off];
        __syncthreads();
    }
    if (threadIdx.x == 0) bsums[blockIdx.x] = sd[0];
}

// scan stage 2+3 fused: every block redundantly scans the <=512 block sums in
// LDS, takes its own base, then does the per-block exclusive scan -> row_ptr.
__global__ void k_scan23(const int* __restrict__ cnt, const int* __restrict__ bsums,
                         int* __restrict__ row_ptr, int N, int nb) {
    __shared__ int sd[256];
    __shared__ int ex[512];
    int t = threadIdx.x;
    // pairwise load of block sums
    int a0 = (2 * t     < nb) ? bsums[2 * t]     : 0;
    int a1 = (2 * t + 1 < nb) ? bsums[2 * t + 1] : 0;
    sd[t] = a0 + a1;
    __syncthreads();
    for (int off = 1; off < 256; off <<= 1) {
        int v = (t >= off) ? sd[t - off] : 0;
        __syncthreads();
        sd[t] += v;
        __syncthreads();
    }
    int pairExcl = (t == 0) ? 0 : sd[t - 1];
    ex[2 * t] = pairExcl;
    ex[2 * t + 1] = pairExcl + a0;
    __syncthreads();
    int myBase = ex[blockIdx.x];
    __syncthreads();
    // per-block scan of cnt
    int i = blockIdx.x * 256 + t;
    int v = (i < N) ? cnt[i] : 0;
    sd[t] = v;
    __syncthreads();
    for (int off = 1; off < 256; off <<= 1) {
        int u = (t >= off) ? sd[t - off] : 0;
        __syncthreads();
        sd[t] += u;
        __syncthreads();
    }
    int excl = sd[t] - v + myBase;
    if (i < N) {
        row_ptr[i] = excl;
        if (i == N - 1) row_ptr[N] = excl + v;
    }
}

// Thread-per-edge, no atomics: pos = row_ptr[row] + rank8[e].
// Pack {col:17b | d_quant:15b}; nontemporal store (avoid line allocate).
__global__ __launch_bounds__(256)
void k_scatter(const int* __restrict__ ei, const float* __restrict__ dist,
               const unsigned char* __restrict__ rank8, const int* __restrict__ row_ptr,
               unsigned int* __restrict__ recs, int E) {
    int e = blockIdx.x * 256 + threadIdx.x;
    if (e >= E) return;
    int row = ei[e], col = ei[E + e];
    float d = dist[e];
    int didx = (int)(d * (32768.0f / CUTOFF) + 0.5f);
    didx = max(0, min(didx, 32767));
    int pos = row_ptr[row] + (int)rank8[e];
    __builtin_nontemporal_store(((unsigned)col << 15) | (unsigned)didx, &recs[pos]);
}

// Sequential pass: decode d-quant, lerp LUT (cache-resident), fp16 fs per layer.
__global__ __launch_bounds__(256)
void k_fs(const unsigned int* __restrict__ recs, const float* __restrict__ lut,
          __half* __restrict__ fs16, int E) {
    int e = blockIdx.x * blockDim.x + threadIdx.x;
    if (e >= E) return;
    unsigned rec = recs[e];
    float td = (float)(rec & 32767u) * (1.0f / 16.0f);
    int i0 = (int)td;
    float fr = td - (float)i0;
#pragma unroll
    for (int l = 0; l < NLAYERS; l++) {
        float f0 = lut[l * LUTSTRIDE + i0];
        float f1 = lut[l * LUTSTRIDE + i0 + 1];
        fs16[(size_t)l * E + e] = __float2half(f0 + fr * (f1 - f0));
    }
}

// Fused layer: phase A aggregates 16 nodes/wave (8 groups x 8 lanes, fp8
// gathers = 1 line/row) into wave-private LDS rows; phase B: 64x64x2 MLP as
// 16 MFMAs (fp16, BN folded in W2'). Residual master hb is fp16, in-place
// (owner-only); fp8 shadow double-buffered. No barriers at all.
__global__ __launch_bounds__(256)
void k_layer2(const int* __restrict__ row_ptr, const unsigned int* __restrict__ recs,
              const __half* __restrict__ fsl, const h8* __restrict__ Wsw,
              const float* __restrict__ b1, const float* __restrict__ b2p,
              const unsigned char* __restrict__ hq_in, unsigned char* __restrict__ hq_out,
              __half* __restrict__ hb, int N) {
    __shared__ _Float16 sA[64 * ASTRIDE];   // 9216 B
    int lane = threadIdx.x & 63;
    int w = threadIdx.x >> 6;
    int base = blockIdx.x * 64 + w * 16;    // this wave's 16 nodes
    int g = lane >> 3, ci = lane & 7;       // 8 groups x 8 lanes

    // ---- phase A: aggregate ----
    for (int i = 0; i < 16; i++) {
        int node = base + i;
        float acc[8] = {0.f, 0.f, 0.f, 0.f, 0.f, 0.f, 0.f, 0.f};
        if (node < N) {
            int s = row_ptr[node], t = row_ptr[node + 1];
            for (int k = s + g; k < t; k += 8) {
                unsigned rec = recs[k];
                int c = rec >> 15;
                float fv = __half2float(fsl[k]);
                union { uint2 u; unsigned char b[8]; } pk;
                pk.u = *(const uint2*)(hq_in + (size_t)c * H + ci * 8);
#pragma unroll
                for (int q = 0; q < 8; q++) {
                    __hip_fp8_e4m3 t8; t8.__x = pk.b[q];
                    acc[q] += fv * (float)t8;
                }
            }
        }
#pragma unroll
        for (int m = 8; m <= 32; m <<= 1) {
#pragma unroll
            for (int j = 0; j < 8; j++) acc[j] += __shfl_xor(acc[j], m, 64);
        }
        if (g == 0) {
            union { uint4 u4; _Float16 hh[8]; } pk;
#pragma unroll
            for (int j = 0; j < 8; j++) pk.hh[j] = (_Float16)acc[j];
            *(uint4*)&sA[(size_t)(w * 16 + i) * ASTRIDE + ci * 8] = pk.u4;
        }
    }
    // wave-private LDS rows: in-wave ds ordering, no barrier needed

    // ---- phase B: MFMA MLP ----
    int q4 = lane >> 4, c16 = lane & 15;
    int rowb = w * 16;
    const h8* WB1 = Wsw;            // frags [kt][nt][lane]
    const h8* WB2 = Wsw + 8 * 64;
    h8 A0 = *(const h8*)&sA[(size_t)(rowb + c16) * ASTRIDE + q4 * 8];
    h8 A1 = *(const h8*)&sA[(size_t)(rowb + c16) * ASTRIDE + 32 + q4 * 8];
    f32x4 C1[4];
#pragma unroll
    for (int nt = 0; nt < 4; nt++) {
        f32x4 c = {0.f, 0.f, 0.f, 0.f};
        c = __builtin_amdgcn_mfma_f32_16x16x32_f16(A0, WB1[nt * 64 + lane], c, 0, 0, 0);
        c = __builtin_amdgcn_mfma_f32_16x16x32_f16(A1, WB1[(4 + nt) * 64 + lane], c, 0, 0, 0);
        C1[nt] = c;
    }
    // softplus -> m1 back into same LDS rows (A-layout for GEMM2)
#pragma unroll
    for (int nt = 0; nt < 4; nt++) {
        float bb = b1[nt * 16 + c16];
#pragma unroll
        for (int reg = 0; reg < 4; reg++) {
            float v = softplus_f(C1[nt][reg] + bb);
            sA[(size_t)(rowb + q4 * 4 + reg) * ASTRIDE + nt * 16 + c16] = (_Float16)v;
        }
    }
    h8 M0 = *(const h8*)&sA[(size_t)(rowb + c16) * ASTRIDE + q4 * 8];
    h8 M1 = *(const h8*)&sA[(size_t)(rowb + c16) * ASTRIDE + 32 + q4 * 8];
    f32x4 C2[4];
#pragma unroll
    for (int nt = 0; nt < 4; nt++) {
        f32x4 c = {0.f, 0.f, 0.f, 0.f};
        c = __builtin_amdgcn_mfma_f32_16x16x32_f16(M0, WB2[nt * 64 + lane], c, 0, 0, 0);
        c = __builtin_amdgcn_mfma_f32_16x16x32_f16(M1, WB2[(4 + nt) * 64 + lane], c, 0, 0, 0);
        C2[nt] = c;
    }
    // epilogue: + b2' (BN folded), fp16 in-place residual, fp8 shadow out
#pragma unroll
    for (int nt = 0; nt < 4; nt++) {
        float bb2 = b2p[nt * 16 + c16];
#pragma unroll
        for (int reg = 0; reg < 4; reg++) {
            int node = base + q4 * 4 + reg;
            if (node < N) {
                size_t idx = (size_t)node * H + nt * 16 + c16;
                float hn = __half2float(hb[idx]) + C2[nt][reg] + bb2;
                hb[idx] = __float2half(hn);
                __hip_fp8_e4m3 q(hn);
                hq_out[idx] = q.__x;
            }
        }
    }
}

// mean + (last block) final MLP chain. gsum accumulated via device atomics;
// last block reads it back on the atomic path and runs the tiny output MLP.
__global__ __launch_bounds__(256)
void k_meanfinal(const __half* __restrict__ hb, float* __restrict__ gsum,
                 int* __restrict__ done, int N,
                 const float* __restrict__ oW1, const float* __restrict__ ob1,
                 const float* __restrict__ og1, const float* __restrict__ obt1,
                 const float* __restrict__ oW2, const float* __restrict__ ob2,
                 const float* __restrict__ og2, const float* __restrict__ obt2,
                 const float* __restrict__ fin_W, const float* __restrict__ fin_b,
                 float* __restrict__ out) {
    __shared__ float s_r[4][H];
    __shared__ int isLast;
    __shared__ float sg[H], su[H / 2], sv[H / 2];
    int lane = threadIdx.x & 63;
    int w = threadIdx.x >> 6;
    int wg = blockIdx.x * 4 + w;
    int stride = gridDim.x * 4;
    float local = 0.f;
    for (int i = wg; i < N; i += stride) local += __half2float(hb[(size_t)i * H + lane]);
    s_r[w][lane] = local;
    __syncthreads();
    if (w == 0) {
        float s = s_r[0][lane] + s_r[1][lane] + s_r[2][lane] + s_r[3][lane];
        atomicAdd(&gsum[lane], s);
    }
    __threadfence();
    if (threadIdx.x == 0) {
        int old = atomicAdd(done, 1);
        isLast = (old == (int)gridDim.x - 1);
    }
    __syncthreads();
    if (!isLast) return;

    int j = threadIdx.x;
    if (j < H) sg[j] = atomicAdd(&gsum[j], 0.0f) / (float)N;
    __syncthreads();
    if (j < H / 2) {
        float acc = ob1[j];
        for (int k = 0; k < H; k++) acc += sg[k] * oW1[k * (H / 2) + j];
        su[j] = softplus_f(acc) * BN_INV * og1[j] + obt1[j];
    }
    __syncthreads();
    if (j < H / 2) {
        float acc = ob2[j];
        for (int k = 0; k < H / 2; k++) acc += su[k] * oW2[k * (H / 2) + j];
        sv[j] = softplus_f(acc) * BN_INV * og2[j] + obt2[j];
    }
    __syncthreads();
    if (j < 3) {
        float acc = fin_b[j];
        for (int k = 0; k < H / 2; k++) acc += sv[k] * fin_W[k * 3 + j];
        out[j] = acc;
    }
}

extern "C" void kernel_launch(void* const* d_in, const int* in_sizes, int n_in,
                              void* d_out, int out_size, void* d_ws, size_t ws_size,
                              hipStream_t stream) {
    const float* x      = (const float*)d_in[0];
    const int*   ei     = (const int*)d_in[1];
    const float* dist   = (const float*)d_in[2];
    /* d_in[3] edge_attr: unused by reference */
    const float* emb_W  = (const float*)d_in[4];
    const float* emb_b  = (const float*)d_in[5];
    const float* fW1    = (const float*)d_in[6];
    const float* fb1    = (const float*)d_in[7];
    const float* fW2    = (const float*)d_in[8];
    const float* fb2    = (const float*)d_in[9];
    const float* iW1    = (const float*)d_in[10];
    const float* ib1    = (const float*)d_in[11];
    const float* iW2    = (const float*)d_in[12];
    const float* ib2    = (const float*)d_in[13];
    const float* bn_g   = (const float*)d_in[14];
    const float* bn_b   = (const float*)d_in[15];
    const float* oW1    = (const float*)d_in[16];
    const float* ob1    = (const float*)d_in[17];
    const float* og1    = (const float*)d_in[18];
    const float* obt1   = (const float*)d_in[19];
    const float* oW2    = (const float*)d_in[20];
    const float* ob2    = (const float*)d_in[21];
    const float* og2    = (const float*)d_in[22];
    const float* obt2   = (const float*)d_in[23];
    const float* fin_W  = (const float*)d_in[24];
    const float* fin_b  = (const float*)d_in[25];
    float* out = (float*)d_out;

    int N = in_sizes[0] / FIN;
    int E = in_sizes[2];
    int nb_scan = (N + 255) / 256;

    // workspace layout (16B-aligned chunks first)
    float*  ws   = (float*)d_ws;
    __half* hb   = (__half*)ws;                            // N*H fp16 (in-place master)
    unsigned char* hq0 = (unsigned char*)(ws + (size_t)N * H / 2);   // N*H fp8
    unsigned char* hq1 = hq0 + (size_t)N * H;                        // N*H fp8
    unsigned int*  recs = (unsigned int*)(hq1 + (size_t)N * H);      // E uint32
    __half* fs16 = (__half*)(recs + E);                    // 3*E half
    h8*     Wsw  = (h8*)(fs16 + (size_t)3 * E);            // 3*2*8*64 h8
    float*  lut  = (float*)(Wsw + NLAYERS * 2 * 8 * 64);   // 3*LUTSTRIDE
    float*  gsum = lut + 3 * LUTSTRIDE;                    // H
    float*  b2p  = gsum + H;                               // L*H
    int*    cnt  = (int*)(b2p + NLAYERS * H);              // N
    int*    row_ptr = cnt + N;                             // N+1
    int*    bsums   = row_ptr + (N + 1);                   // nb_scan (<=512)
    int*    done    = bsums + 512;                         // 1 (+pad)
    unsigned char* rank8 = (unsigned char*)(done + 4);     // E bytes

    int nbE = (N + 3) / 4;
    int nb_setup = nbE + NLAYERS * LUTB + 12;
    k_setup<<<nb_setup, 256, 0, stream>>>(x, emb_W, emb_b, hb, hq0,
                                          fW1, fb1, fW2, fb2, iW1, iW2,
                                          bn_g, bn_b, ib2, Wsw, b2p, lut,
                                          cnt, gsum, done, N);

    int nb_edge = (E + 255) / 256;
    k_hist<<<nb_edge, 256, 0, stream>>>(ei, cnt, rank8, E);
    k_scan1<<<nb_scan, 256, 0, stream>>>(cnt, bsums, N);
    k_scan23<<<nb_scan, 256, 0, stream>>>(cnt, bsums, row_ptr, N, nb_scan);

    k_scatter<<<nb_edge, 256, 0, stream>>>(ei, dist, rank8, row_ptr, recs, E);
    k_fs<<<nb_edge, 256, 0, stream>>>(recs, lut, fs16, E);

    unsigned char* hqp[2] = {hq0, hq1};
    int nb_tile = (N + 63) / 64;
    for (int l = 0; l < NLAYERS; l++) {
        k_layer2<<<nb_tile, 256, 0, stream>>>(row_ptr, recs, fs16 + (size_t)l * E,
                                              Wsw + (size_t)l * 1024,
                                              ib1 + l * H, b2p + l * H,
                                              hqp[l & 1], hqp[(l + 1) & 1], hb, N);
    }

    k_meanfinal<<<1024, 256, 0, stream>>>(hb, gsum, done, N,
                                          oW1, ob1, og1, obt1, oW2, ob2, og2, obt2,
                                          fin_W, fin_b, out);
}

// Round 11
// 496.412 us; speedup vs baseline: 1.0535x; 1.0535x over previous
//
#include <hip/hip_runtime.h>
#include <hip/hip_fp16.h>
#include <hip/hip_fp8.h>
#include <math.h>

#define CUTOFF 5.0f
#define H 64
#define FIN 16
#define NLAYERS 3
#define LUTN 2048          // intervals; table has LUTN+1 entries
#define LUTSTRIDE 2052     // padded per-layer stride
#define ASTRIDE 72         // LDS row stride in halves (pad 64->72: <=2-way conflicts)
#define NPART 8            // histogram partitions (== XCD count)
#define MEANB 256          // blocks in mean pass (partials rows)

// 1/sqrt(1 + 1e-3)  (BN inference, moving mean 0 / var 1)
#define BN_INV 0.999500374750f

typedef _Float16 h8 __attribute__((ext_vector_type(8)));
typedef float f32x4 __attribute__((ext_vector_type(4)));

__device__ __forceinline__ float softplus_f(float x) {
    return fmaxf(x, 0.f) + __logf(1.f + __expf(-fabsf(x)));
}

// Precompute rowsum(fW2[l]) and sum(fb2[l])
__global__ void k_wsum(const float* __restrict__ fW2, const float* __restrict__ fb2,
                       float* __restrict__ wsum, float* __restrict__ bsum) {
    int tid = threadIdx.x;
    if (tid < NLAYERS * H) {
        int l = tid >> 6, hh = tid & 63;
        float s = 0.f;
        for (int j = 0; j < H; j++) s += fW2[l * H * H + hh * H + j];
        wsum[tid] = s;
    }
    if (tid < NLAYERS) {
        float s = 0.f;
        for (int j = 0; j < H; j++) s += fb2[tid * H + j];
        bsum[tid] = s;
    }
}

// Tabulate g_l(d) over [0, CUTOFF]; lerp error ~1e-6.
__global__ void k_lut(const float* __restrict__ fW1, const float* __restrict__ fb1,
                      const float* __restrict__ wsum, const float* __restrict__ bsum,
                      float* __restrict__ lut) {
    int t = blockIdx.x * blockDim.x + threadIdx.x;
    if (t >= NLAYERS * (LUTN + 1)) return;
    int l = t / (LUTN + 1), i = t % (LUTN + 1);
    float d = (float)i * (CUTOFF / (float)LUTN);
    float scaled = d * (2.0f / CUTOFF) - 1.0f;
    float cut = 0.5f * (__cosf(d * (3.14159265358979f / CUTOFF)) + 1.0f);
    if (d > CUTOFF) cut = 0.f;
    float s = 0.f;
    for (int hh = 0; hh < H; hh++) {
        int wi = l * H + hh;
        s += tanhf(scaled * fW1[wi] + fb1[wi]) * wsum[wi];
    }
    lut[l * LUTSTRIDE + i] = cut * (s + bsum[l]);
}

// Pre-swizzle W1/W2 into MFMA B-fragment order (fp16), folding BN into W2;
// also compute b2' = b2*inv*gamma + beta.
// B-frag (16x16x32_f16): lane holds B[k = kt*32 + (lane>>4)*8 + j][n = nt*16 + (lane&15)]
__global__ void k_prep(const float* __restrict__ iW1, const float* __restrict__ iW2,
                       const float* __restrict__ gamma, const float* __restrict__ beta,
                       const float* __restrict__ ib2, h8* __restrict__ Wsw,
                       float* __restrict__ b2p) {
    int tid = blockIdx.x * blockDim.x + threadIdx.x;
    if (tid < NLAYERS * H) b2p[tid] = ib2[tid] * BN_INV * gamma[tid] + beta[tid];
    if (tid >= NLAYERS * 2 * 8 * 64) return;
    int lane = tid & 63;
    int frag = (tid >> 6) & 7;
    int mat  = (tid >> 9) & 1;
    int l    = tid >> 10;
    int kt = frag >> 2, nt = frag & 3;
    int n = nt * 16 + (lane & 15);
    int k0 = kt * 32 + (lane >> 4) * 8;
    const float* W = (mat ? iW2 : iW1) + l * H * H;
    float scale = mat ? BN_INV * gamma[l * H + n] : 1.0f;
    h8 v;
#pragma unroll
    for (int j = 0; j < 8; j++) v[j] = (_Float16)(W[(k0 + j) * H + n] * scale);
    Wsw[tid] = v;
}

// h = x @ emb_W + emb_b -> fp16 residual master + fp8 gather shadow
__global__ void k_embed(const float* __restrict__ x, const float* __restrict__ emb_W,
                        const float* __restrict__ emb_b, __half* __restrict__ hb,
                        unsigned char* __restrict__ hq, int N) {
    int lane = threadIdx.x & 63;
    int w = threadIdx.x >> 6;
    int node = blockIdx.x * 4 + w;
    if (node >= N) return;
    float acc = emb_b[lane];
#pragma unroll
    for (int k = 0; k < FIN; k++) acc += x[node * FIN + k] * emb_W[k * H + lane];
    size_t idx = (size_t)node * H + lane;
    hb[idx] = __float2half(acc);
    __hip_fp8_e4m3 q(acc);
    hq[idx] = q.__x;
}

// Partitioned histogram: partition p = blockIdx%8. Atomic return value
// is the within-(partition,row) rank.
__global__ __launch_bounds__(256)
void k_hist(const int* __restrict__ ei, int* __restrict__ cnt8,
            unsigned char* __restrict__ rank8, int N, int E) {
    int e = blockIdx.x * 256 + threadIdx.x;
    if (e < E) {
        int p = blockIdx.x & (NPART - 1);
        int r = atomicAdd(&cnt8[(size_t)p * N + ei[e]], 1);
        rank8[e] = (unsigned char)r;
    }
}

// ---- hierarchical exclusive scan over row totals -> row_ptr[N+1] + per-
// partition bases base[p][row] = row_ptr[row] + prefix_p ----
__global__ void k_scan1(const int* __restrict__ cnt8, int* __restrict__ bsums, int N) {
    __shared__ int sd[256];
    int i = blockIdx.x * 256 + threadIdx.x;
    int v = 0;
    if (i < N) {
#pragma unroll
        for (int p = 0; p < NPART; p++) v += cnt8[(size_t)p * N + i];
    }
    sd[threadIdx.x] = v;
    __syncthreads();
    for (int off = 128; off > 0; off >>= 1) {
        if (threadIdx.x < off) sd[threadIdx.x] += sd[threadIdx.x + off];
        __syncthreads();
    }
    if (threadIdx.x == 0) bsums[blockIdx.x] = sd[0];
}

__global__ void k_scan2(int* __restrict__ bsums, int nb) {
    __shared__ int sp[256];
    int t = threadIdx.x;
    int chunk = (nb + 255) / 256;
    int lo = t * chunk, hi = min(lo + chunk, nb);
    int s = 0;
    for (int i = lo; i < hi; i++) s += bsums[i];
    sp[t] = s;
    __syncthreads();
    for (int off = 1; off < 256; off <<= 1) {
        int v = (t >= off) ? sp[t - off] : 0;
        __syncthreads();
        sp[t] += v;
        __syncthreads();
    }
    int run = (t == 0) ? 0 : sp[t - 1];
    for (int i = lo; i < hi; i++) {
        int c = bsums[i];
        bsums[i] = run;
        run += c;
    }
}

__global__ void k_scan3(const int* __restrict__ cnt8, const int* __restrict__ bsums,
                        int* __restrict__ row_ptr, int* __restrict__ base, int N) {
    __shared__ int sd[256];
    int b = blockIdx.x;
    int i = b * 256 + threadIdx.x;
    int c[NPART];
    int v = 0;
    if (i < N) {
#pragma unroll
        for (int p = 0; p < NPART; p++) { c[p] = cnt8[(size_t)p * N + i]; v += c[p]; }
    }
    sd[threadIdx.x] = v;
    __syncthreads();
    for (int off = 1; off < 256; off <<= 1) {
        int u = (threadIdx.x >= off) ? sd[threadIdx.x - off] : 0;
        __syncthreads();
        sd[threadIdx.x] += u;
        __syncthreads();
    }
    int excl = sd[threadIdx.x] - v + bsums[b];
    if (i < N) {
        row_ptr[i] = excl;
        int run = excl;
#pragma unroll
        for (int p = 0; p < NPART; p++) { base[(size_t)p * N + i] = run; run += c[p]; }
        if (i == N - 1) row_ptr[N] = excl + v;
    }
}

// Thread-per-edge, no atomics: pos = base[p][row] + rank8[e] (p matches k_hist).
// Pack {col:17b | d_quant:15b}; nontemporal store (avoid line allocate).
__global__ __launch_bounds__(256)
void k_scatter(const int* __restrict__ ei, const float* __restrict__ dist,
               const unsigned char* __restrict__ rank8, const int* __restrict__ base,
               unsigned int* __restrict__ recs, int N, int E) {
    int e = blockIdx.x * 256 + threadIdx.x;
    if (e >= E) return;
    int p = blockIdx.x & (NPART - 1);
    int row = ei[e], col = ei[E + e];
    float d = dist[e];
    int didx = (int)(d * (32768.0f / CUTOFF) + 0.5f);
    didx = max(0, min(didx, 32767));
    int pos = base[(size_t)p * N + row] + (int)rank8[e];
    __builtin_nontemporal_store(((unsigned)col << 15) | (unsigned)didx, &recs[pos]);
}

// Sequential pass: decode d-quant, lerp LUT (cache-resident), fp16 fs per layer.
__global__ __launch_bounds__(256)
void k_fs(const unsigned int* __restrict__ recs, const float* __restrict__ lut,
          __half* __restrict__ fs16, int E) {
    int e = blockIdx.x * blockDim.x + threadIdx.x;
    if (e >= E) return;
    unsigned rec = recs[e];
    float td = (float)(rec & 32767u) * (1.0f / 16.0f);
    int i0 = (int)td;
    float fr = td - (float)i0;
#pragma unroll
    for (int l = 0; l < NLAYERS; l++) {
        float f0 = lut[l * LUTSTRIDE + i0];
        float f1 = lut[l * LUTSTRIDE + i0 + 1];
        fs16[(size_t)l * E + e] = __float2half(f0 + fr * (f1 - f0));
    }
}

// Fused layer: phase A aggregates 16 nodes/wave (8 groups x 8 lanes, fp8
// gathers = 1 line/row) into wave-private LDS rows; phase B: 64x64x2 MLP as
// 16 MFMAs (fp16, BN folded in W2'). Residual master hb is fp16, in-place
// (owner-only); fp8 shadow double-buffered. No barriers at all.
__global__ __launch_bounds__(256)
void k_layer2(const int* __restrict__ row_ptr, const unsigned int* __restrict__ recs,
              const __half* __restrict__ fsl, const h8* __restrict__ Wsw,
              const float* __restrict__ b1, const float* __restrict__ b2p,
              const unsigned char* __restrict__ hq_in, unsigned char* __restrict__ hq_out,
              __half* __restrict__ hb, int N) {
    __shared__ _Float16 sA[64 * ASTRIDE];   // 9216 B
    int lane = threadIdx.x & 63;
    int w = threadIdx.x >> 6;
    int base = blockIdx.x * 64 + w * 16;    // this wave's 16 nodes
    int g = lane >> 3, ci = lane & 7;       // 8 groups x 8 lanes

    // ---- phase A: aggregate ----
    for (int i = 0; i < 16; i++) {
        int node = base + i;
        float acc[8] = {0.f, 0.f, 0.f, 0.f, 0.f, 0.f, 0.f, 0.f};
        if (node < N) {
            int s = row_ptr[node], t = row_ptr[node + 1];
            for (int k = s + g; k < t; k += 8) {
                unsigned rec = recs[k];
                int c = rec >> 15;
                float fv = __half2float(fsl[k]);
                union { uint2 u; unsigned char b[8]; } pk;
                pk.u = *(const uint2*)(hq_in + (size_t)c * H + ci * 8);
#pragma unroll
                for (int q = 0; q < 8; q++) {
                    __hip_fp8_e4m3 t8; t8.__x = pk.b[q];
                    acc[q] += fv * (float)t8;
                }
            }
        }
#pragma unroll
        for (int m = 8; m <= 32; m <<= 1) {
#pragma unroll
            for (int j = 0; j < 8; j++) acc[j] += __shfl_xor(acc[j], m, 64);
        }
        if (g == 0) {
            union { uint4 u4; _Float16 hh[8]; } pk;
#pragma unroll
            for (int j = 0; j < 8; j++) pk.hh[j] = (_Float16)acc[j];
            *(uint4*)&sA[(size_t)(w * 16 + i) * ASTRIDE + ci * 8] = pk.u4;
        }
    }
    // wave-private LDS rows: in-wave ds ordering, no barrier needed

    // ---- phase B: MFMA MLP ----
    int q4 = lane >> 4, c16 = lane & 15;
    int rowb = w * 16;
    const h8* WB1 = Wsw;            // frags [kt][nt][lane]
    const h8* WB2 = Wsw + 8 * 64;
    h8 A0 = *(const h8*)&sA[(size_t)(rowb + c16) * ASTRIDE + q4 * 8];
    h8 A1 = *(const h8*)&sA[(size_t)(rowb + c16) * ASTRIDE + 32 + q4 * 8];
    f32x4 C1[4];
#pragma unroll
    for (int nt = 0; nt < 4; nt++) {
        f32x4 c = {0.f, 0.f, 0.f, 0.f};
        c = __builtin_amdgcn_mfma_f32_16x16x32_f16(A0, WB1[nt * 64 + lane], c, 0, 0, 0);
        c = __builtin_amdgcn_mfma_f32_16x16x32_f16(A1, WB1[(4 + nt) * 64 + lane], c, 0, 0, 0);
        C1[nt] = c;
    }
    // softplus -> m1 back into same LDS rows (A-layout for GEMM2)
#pragma unroll
    for (int nt = 0; nt < 4; nt++) {
        float bb = b1[nt * 16 + c16];
#pragma unroll
        for (int reg = 0; reg < 4; reg++) {
            float v = softplus_f(C1[nt][reg] + bb);
            sA[(size_t)(rowb + q4 * 4 + reg) * ASTRIDE + nt * 16 + c16] = (_Float16)v;
        }
    }
    h8 M0 = *(const h8*)&sA[(size_t)(rowb + c16) * ASTRIDE + q4 * 8];
    h8 M1 = *(const h8*)&sA[(size_t)(rowb + c16) * ASTRIDE + 32 + q4 * 8];
    f32x4 C2[4];
#pragma unroll
    for (int nt = 0; nt < 4; nt++) {
        f32x4 c = {0.f, 0.f, 0.f, 0.f};
        c = __builtin_amdgcn_mfma_f32_16x16x32_f16(M0, WB2[nt * 64 + lane], c, 0, 0, 0);
        c = __builtin_amdgcn_mfma_f32_16x16x32_f16(M1, WB2[(4 + nt) * 64 + lane], c, 0, 0, 0);
        C2[nt] = c;
    }
    // epilogue: + b2' (BN folded), fp16 in-place residual, fp8 shadow out
#pragma unroll
    for (int nt = 0; nt < 4; nt++) {
        float bb2 = b2p[nt * 16 + c16];
#pragma unroll
        for (int reg = 0; reg < 4; reg++) {
            int node = base + q4 * 4 + reg;
            if (node < N) {
                size_t idx = (size_t)node * H + nt * 16 + c16;
                float hn = __half2float(hb[idx]) + C2[nt][reg] + bb2;
                hb[idx] = __float2half(hn);
                __hip_fp8_e4m3 q(hn);
                hq_out[idx] = q.__x;
            }
        }
    }
}

// Stage 1 of mean: per-block partial sums to DISTINCT rows — no atomics.
__global__ __launch_bounds__(256)
void k_mean(const __half* __restrict__ hb, float* __restrict__ partials, int N) {
    __shared__ float s_r[4][H];
    int lane = threadIdx.x & 63;
    int w = threadIdx.x >> 6;
    int wg = blockIdx.x * 4 + w;
    int stride = gridDim.x * 4;
    float local = 0.f;
    for (int i = wg; i < N; i += stride) local += __half2float(hb[(size_t)i * H + lane]);
    s_r[w][lane] = local;
    __syncthreads();
    if (w == 0) {
        float s = s_r[0][lane] + s_r[1][lane] + s_r[2][lane] + s_r[3][lane];
        partials[(size_t)blockIdx.x * H + lane] = s;
    }
}

// Stage 2: one block reduces MEANB partial rows, then the tiny output MLP.
__global__ __launch_bounds__(256)
void k_final(const float* __restrict__ partials, int N,
             const float* __restrict__ oW1, const float* __restrict__ ob1,
             const float* __restrict__ og1, const float* __restrict__ obt1,
             const float* __restrict__ oW2, const float* __restrict__ ob2,
             const float* __restrict__ og2, const float* __restrict__ obt2,
             const float* __restrict__ fin_W, const float* __restrict__ fin_b,
             float* __restrict__ out) {
    __shared__ float red[4][H];
    __shared__ float sg[H], su[H / 2], sv[H / 2];
    int t = threadIdx.x;
    int ch = t & 63, grp = t >> 6;
    float s = 0.f;
    for (int b = grp; b < MEANB; b += 4) s += partials[(size_t)b * H + ch];
    red[grp][ch] = s;
    __syncthreads();
    if (t < H) sg[t] = (red[0][t] + red[1][t] + red[2][t] + red[3][t]) / (float)N;
    __syncthreads();
    int j = t;
    if (j < H / 2) {
        float acc = ob1[j];
        for (int k = 0; k < H; k++) acc += sg[k] * oW1[k * (H / 2) + j];
        su[j] = softplus_f(acc) * BN_INV * og1[j] + obt1[j];
    }
    __syncthreads();
    if (j < H / 2) {
        float acc = ob2[j];
        for (int k = 0; k < H / 2; k++) acc += su[k] * oW2[k * (H / 2) + j];
        sv[j] = softplus_f(acc) * BN_INV * og2[j] + obt2[j];
    }
    __syncthreads();
    if (j < 3) {
        float acc = fin_b[j];
        for (int k = 0; k < H / 2; k++) acc += sv[k] * fin_W[k * 3 + j];
        out[j] = acc;
    }
}

extern "C" void kernel_launch(void* const* d_in, const int* in_sizes, int n_in,
                              void* d_out, int out_size, void* d_ws, size_t ws_size,
                              hipStream_t stream) {
    const float* x      = (const float*)d_in[0];
    const int*   ei     = (const int*)d_in[1];
    const float* dist   = (const float*)d_in[2];
    /* d_in[3] edge_attr: unused by reference */
    const float* emb_W  = (const float*)d_in[4];
    const float* emb_b  = (const float*)d_in[5];
    const float* fW1    = (const float*)d_in[6];
    const float* fb1    = (const float*)d_in[7];
    const float* fW2    = (const float*)d_in[8];
    const float* fb2    = (const float*)d_in[9];
    const float* iW1    = (const float*)d_in[10];
    const float* ib1    = (const float*)d_in[11];
    const float* iW2    = (const float*)d_in[12];
    const float* ib2    = (const float*)d_in[13];
    const float* bn_g   = (const float*)d_in[14];
    const float* bn_b   = (const float*)d_in[15];
    const float* oW1    = (const float*)d_in[16];
    const float* ob1    = (const float*)d_in[17];
    const float* og1    = (const float*)d_in[18];
    const float* obt1   = (const float*)d_in[19];
    const float* oW2    = (const float*)d_in[20];
    const float* ob2    = (const float*)d_in[21];
    const float* og2    = (const float*)d_in[22];
    const float* obt2   = (const float*)d_in[23];
    const float* fin_W  = (const float*)d_in[24];
    const float* fin_b  = (const float*)d_in[25];
    float* out = (float*)d_out;

    int N = in_sizes[0] / FIN;
    int E = in_sizes[2];
    int nb_scan = (N + 255) / 256;

    // workspace layout (16B-aligned chunks first)
    float*  ws   = (float*)d_ws;
    __half* hb   = (__half*)ws;                            // N*H fp16 (in-place master)
    unsigned char* hq0 = (unsigned char*)(ws + (size_t)N * H / 2);   // N*H fp8
    unsigned char* hq1 = hq0 + (size_t)N * H;                        // N*H fp8
    unsigned int*  recs = (unsigned int*)(hq1 + (size_t)N * H);      // E uint32
    __half* fs16 = (__half*)(recs + E);                    // 3*E half
    h8*     Wsw  = (h8*)(fs16 + (size_t)3 * E);            // 3*2*8*64 h8
    float*  lut  = (float*)(Wsw + NLAYERS * 2 * 8 * 64);   // 3*LUTSTRIDE
    float*  wsum = lut + 3 * LUTSTRIDE;                    // L*H
    float*  bsum = wsum + NLAYERS * H;                     // L (+pad to 8)
    float*  partials = bsum + 8;                           // MEANB*H
    float*  b2p  = partials + MEANB * H;                   // L*H
    int*    cnt8 = (int*)(b2p + NLAYERS * H);              // NPART*N
    int*    basep = cnt8 + (size_t)NPART * N;              // NPART*N
    int*    row_ptr = basep + (size_t)NPART * N;           // N+1
    int*    bsums   = row_ptr + (N + 1);                   // nb_scan
    unsigned char* rank8 = (unsigned char*)(bsums + nb_scan);  // E bytes

    hipMemsetAsync(cnt8, 0, (size_t)NPART * N * sizeof(int), stream);

    k_wsum<<<1, 256, 0, stream>>>(fW2, fb2, wsum, bsum);
    k_lut<<<(NLAYERS * (LUTN + 1) + 255) / 256, 256, 0, stream>>>(fW1, fb1, wsum, bsum, lut);
    k_prep<<<(NLAYERS * 2 * 8 * 64 + 255) / 256, 256, 0, stream>>>(iW1, iW2, bn_g, bn_b,
                                                                   ib2, Wsw, b2p);

    int nb_node = (N + 3) / 4;
    k_embed<<<nb_node, 256, 0, stream>>>(x, emb_W, emb_b, hb, hq0, N);

    int nb_edge = (E + 255) / 256;
    k_hist<<<nb_edge, 256, 0, stream>>>(ei, cnt8, rank8, N, E);
    k_scan1<<<nb_scan, 256, 0, stream>>>(cnt8, bsums, N);
    k_scan2<<<1, 256, 0, stream>>>(bsums, nb_scan);
    k_scan3<<<nb_scan, 256, 0, stream>>>(cnt8, bsums, row_ptr, basep, N);

    k_scatter<<<nb_edge, 256, 0, stream>>>(ei, dist, rank8, basep, recs, N, E);
    k_fs<<<nb_edge, 256, 0, stream>>>(recs, lut, fs16, E);

    unsigned char* hqp[2] = {hq0, hq1};
    int nb_tile = (N + 63) / 64;
    for (int l = 0; l < NLAYERS; l++) {
        k_layer2<<<nb_tile, 256, 0, stream>>>(row_ptr, recs, fs16 + (size_t)l * E,
                                              Wsw + (size_t)l * 1024,
                                              ib1 + l * H, b2p + l * H,
                                              hqp[l & 1], hqp[(l + 1) & 1], hb, N);
    }

    k_mean<<<MEANB, 256, 0, stream>>>(hb, partials, N);
    k_final<<<1, 256, 0, stream>>>(partials, N, oW1, ob1, og1, obt1,
                                   oW2, ob2, og2, obt2, fin_W, fin_b, out);
}

// Round 12
// 482.162 us; speedup vs baseline: 1.0846x; 1.0296x over previous
//
#include <hip/hip_runtime.h>
#include <hip/hip_fp16.h>
#include <hip/hip_fp8.h>
#include <math.h>

#define CUTOFF 5.0f
#define H 64
#define FIN 16
#define NLAYERS 3
#define LUTN 2048          // intervals; table has LUTN+1 entries
#define LUTSTRIDE 2052     // padded per-layer stride
#define ASTRIDE 72         // LDS row stride in halves (pad 64->72: <=2-way conflicts)
#define NPART 8            // histogram partitions (== XCD count)
#define MEANB 256          // blocks in mean pass (partials rows)
#define LUTB 9             // lut blocks per layer (9*256 >= 2049)

// 1/sqrt(1 + 1e-3)  (BN inference, moving mean 0 / var 1)
#define BN_INV 0.999500374750f

typedef _Float16 h8 __attribute__((ext_vector_type(8)));
typedef float f32x4 __attribute__((ext_vector_type(4)));

__device__ __forceinline__ float softplus_f(float x) {
    return fmaxf(x, 0.f) + __logf(1.f + __expf(-fabsf(x)));
}

// ---- K1: mega setup. Block roles by blockIdx range:
//   [0, nbE)                 embed 4 nodes/block -> hb fp16 + hq fp8; zero 32 cnt8 ints
//   [nbE, nbE+27)            LUT: inline wsum/bsum in LDS, 256 entries/block
//   [nbE+27, nbE+39)         weight swizzle Wsw + b2p
__global__ __launch_bounds__(256)
void k_setup(const float* __restrict__ x, const float* __restrict__ emb_W,
             const float* __restrict__ emb_b, __half* __restrict__ hb,
             unsigned char* __restrict__ hq,
             const float* __restrict__ fW1, const float* __restrict__ fb1,
             const float* __restrict__ fW2, const float* __restrict__ fb2,
             const float* __restrict__ iW1, const float* __restrict__ iW2,
             const float* __restrict__ bn_g, const float* __restrict__ bn_b,
             const float* __restrict__ ib2, h8* __restrict__ Wsw,
             float* __restrict__ b2p, float* __restrict__ lut,
             int* __restrict__ cnt8, int N) {
    __shared__ float swsum[64];
    __shared__ float sbsum;
    int b = blockIdx.x;
    int t = threadIdx.x;
    int nbE = (N + 3) / 4;
    if (b < nbE) {
        // zero a 32-int slice of cnt8 (flat 8N ints; nbE*32 >= 8N)
        int ci = b * 32 + t;
        if (t < 32 && ci < NPART * N) cnt8[ci] = 0;
        // embed
        int lane = t & 63;
        int w = t >> 6;
        int node = b * 4 + w;
        if (node < N) {
            float acc = emb_b[lane];
#pragma unroll
            for (int k = 0; k < FIN; k++) acc += x[node * FIN + k] * emb_W[k * H + lane];
            size_t idx = (size_t)node * H + lane;
            hb[idx] = __float2half(acc);
            __hip_fp8_e4m3 q(acc);
            hq[idx] = q.__x;
        }
    } else if (b < nbE + NLAYERS * LUTB) {
        int lb = b - nbE;
        int l = lb / LUTB, part = lb % LUTB;
        if (t < 64) {
            float s = 0.f;
            for (int j = 0; j < H; j++) s += fW2[l * H * H + t * H + j];
            swsum[t] = s;
        }
        if (t == 64) {
            float s = 0.f;
            for (int j = 0; j < H; j++) s += fb2[l * H + j];
            sbsum = s;
        }
        __syncthreads();
        int i = part * 256 + t;
        if (i <= LUTN) {
            float d = (float)i * (CUTOFF / (float)LUTN);
            float scaled = d * (2.0f / CUTOFF) - 1.0f;
            float cut = 0.5f * (__cosf(d * (3.14159265358979f / CUTOFF)) + 1.0f);
            if (d > CUTOFF) cut = 0.f;
            float s = 0.f;
            for (int hh = 0; hh < H; hh++) {
                int wi = l * H + hh;
                s += tanhf(scaled * fW1[wi] + fb1[wi]) * swsum[hh];
            }
            lut[l * LUTSTRIDE + i] = cut * (s + sbsum);
        }
    } else {
        int tid = (b - nbE - NLAYERS * LUTB) * 256 + t;
        if (tid < NLAYERS * H)
            b2p[tid] = ib2[tid] * BN_INV * bn_g[tid] + bn_b[tid];
        if (tid < NLAYERS * 2 * 8 * 64) {
            int lane = tid & 63;
            int frag = (tid >> 6) & 7;
            int mat  = (tid >> 9) & 1;
            int l    = tid >> 10;
            int kt = frag >> 2, nt = frag & 3;
            int n = nt * 16 + (lane & 15);
            int k0 = kt * 32 + (lane >> 4) * 8;
            const float* W = (mat ? iW2 : iW1) + l * H * H;
            float scale = mat ? BN_INV * bn_g[l * H + n] : 1.0f;
            h8 v;
#pragma unroll
            for (int j = 0; j < 8; j++) v[j] = (_Float16)(W[(k0 + j) * H + n] * scale);
            Wsw[tid] = v;
        }
    }
}

// Partitioned histogram: partition p = blockIdx%8. Atomic return value
// is the within-(partition,row) rank.
__global__ __launch_bounds__(256)
void k_hist(const int* __restrict__ ei, int* __restrict__ cnt8,
            unsigned char* __restrict__ rank8, int N, int E) {
    int e = blockIdx.x * 256 + threadIdx.x;
    if (e < E) {
        int p = blockIdx.x & (NPART - 1);
        int r = atomicAdd(&cnt8[(size_t)p * N + ei[e]], 1);
        rank8[e] = (unsigned char)r;
    }
}

// scan stage 1: per-256-row block sums of the row totals (8 partitions summed)
__global__ void k_scan1(const int* __restrict__ cnt8, int* __restrict__ bsums, int N) {
    __shared__ int sd[256];
    int i = blockIdx.x * 256 + threadIdx.x;
    int v = 0;
    if (i < N) {
#pragma unroll
        for (int p = 0; p < NPART; p++) v += cnt8[(size_t)p * N + i];
    }
    sd[threadIdx.x] = v;
    __syncthreads();
    for (int off = 128; off > 0; off >>= 1) {
        if (threadIdx.x < off) sd[threadIdx.x] += sd[threadIdx.x + off];
        __syncthreads();
    }
    if (threadIdx.x == 0) bsums[blockIdx.x] = sd[0];
}

// scan stage 2+3 fused: every block redundantly scans the <=512 block sums in
// LDS, takes its own base, then per-block scan of row totals -> row_ptr and
// per-partition bases base[p][row].
__global__ void k_scan23(const int* __restrict__ cnt8, const int* __restrict__ bsums,
                         int* __restrict__ row_ptr, int* __restrict__ base,
                         int N, int nb) {
    __shared__ int sd[256];
    __shared__ int ex[512];
    int t = threadIdx.x;
    int a0 = (2 * t     < nb) ? bsums[2 * t]     : 0;
    int a1 = (2 * t + 1 < nb) ? bsums[2 * t + 1] : 0;
    sd[t] = a0 + a1;
    __syncthreads();
    for (int off = 1; off < 256; off <<= 1) {
        int v = (t >= off) ? sd[t - off] : 0;
        __syncthreads();
        sd[t] += v;
        __syncthreads();
    }
    int pairExcl = (t == 0) ? 0 : sd[t - 1];
    ex[2 * t] = pairExcl;
    ex[2 * t + 1] = pairExcl + a0;
    __syncthreads();
    int myBase = ex[blockIdx.x];
    __syncthreads();

    int i = blockIdx.x * 256 + t;
    int c[NPART];
    int v = 0;
    if (i < N) {
#pragma unroll
        for (int p = 0; p < NPART; p++) { c[p] = cnt8[(size_t)p * N + i]; v += c[p]; }
    }
    sd[t] = v;
    __syncthreads();
    for (int off = 1; off < 256; off <<= 1) {
        int u = (t >= off) ? sd[t - off] : 0;
        __syncthreads();
        sd[t] += u;
        __syncthreads();
    }
    int excl = sd[t] - v + myBase;
    if (i < N) {
        row_ptr[i] = excl;
        int run = excl;
#pragma unroll
        for (int p = 0; p < NPART; p++) { base[(size_t)p * N + i] = run; run += c[p]; }
        if (i == N - 1) row_ptr[N] = excl + v;
    }
}

// Thread-per-edge, no atomics: pos = base[p][row] + rank8[e] (p matches k_hist).
// Pack {col:17b | d_quant:15b}; nontemporal store (avoid line allocate).
__global__ __launch_bounds__(256)
void k_scatter(const int* __restrict__ ei, const float* __restrict__ dist,
               const unsigned char* __restrict__ rank8, const int* __restrict__ base,
               unsigned int* __restrict__ recs, int N, int E) {
    int e = blockIdx.x * 256 + threadIdx.x;
    if (e >= E) return;
    int p = blockIdx.x & (NPART - 1);
    int row = ei[e], col = ei[E + e];
    float d = dist[e];
    int didx = (int)(d * (32768.0f / CUTOFF) + 0.5f);
    didx = max(0, min(didx, 32767));
    int pos = base[(size_t)p * N + row] + (int)rank8[e];
    __builtin_nontemporal_store(((unsigned)col << 15) | (unsigned)didx, &recs[pos]);
}

// Fused layer: LDS LUT (fs lerped inline from rec d-quant); phase A aggregates
// 16 nodes/wave (8 groups x 8 lanes, fp8 gathers = 1 line/row) into wave-
// private LDS rows; phase B: 64x64x2 MLP as 16 MFMAs (fp16, BN folded in W2').
// Residual master hb fp16 in-place (owner-only); fp8 shadow double-buffered.
__global__ __launch_bounds__(256)
void k_layer(const int* __restrict__ row_ptr, const unsigned int* __restrict__ recs,
             const float* __restrict__ lutl, const h8* __restrict__ Wsw,
             const float* __restrict__ b1, const float* __restrict__ b2p,
             const unsigned char* __restrict__ hq_in, unsigned char* __restrict__ hq_out,
             __half* __restrict__ hb, int N) {
    __shared__ float s_lut[LUTN + 1];       // 8196 B
    __shared__ _Float16 sA[64 * ASTRIDE];   // 9216 B
    for (int i = threadIdx.x; i <= LUTN; i += 256) s_lut[i] = lutl[i];
    __syncthreads();

    int lane = threadIdx.x & 63;
    int w = threadIdx.x >> 6;
    int base = blockIdx.x * 64 + w * 16;    // this wave's 16 nodes
    int g = lane >> 3, ci = lane & 7;       // 8 groups x 8 lanes

    // ---- phase A: aggregate ----
    for (int i = 0; i < 16; i++) {
        int node = base + i;
        float acc[8] = {0.f, 0.f, 0.f, 0.f, 0.f, 0.f, 0.f, 0.f};
        if (node < N) {
            int s = row_ptr[node], t = row_ptr[node + 1];
            for (int k = s + g; k < t; k += 8) {
                unsigned rec = recs[k];
                int c = rec >> 15;
                float td = (float)(rec & 32767u) * (1.0f / 16.0f);
                int i0 = (int)td;
                float fr = td - (float)i0;
                float f0 = s_lut[i0];
                float fv = f0 + fr * (s_lut[i0 + 1] - f0);
                union { uint2 u; unsigned char b[8]; } pk;
                pk.u = *(const uint2*)(hq_in + (size_t)c * H + ci * 8);
#pragma unroll
                for (int q = 0; q < 8; q++) {
                    __hip_fp8_e4m3 t8; t8.__x = pk.b[q];
                    acc[q] += fv * (float)t8;
                }
            }
        }
#pragma unroll
        for (int m = 8; m <= 32; m <<= 1) {
#pragma unroll
            for (int j = 0; j < 8; j++) acc[j] += __shfl_xor(acc[j], m, 64);
        }
        if (g == 0) {
            union { uint4 u4; _Float16 hh[8]; } pk;
#pragma unroll
            for (int j = 0; j < 8; j++) pk.hh[j] = (_Float16)acc[j];
            *(uint4*)&sA[(size_t)(w * 16 + i) * ASTRIDE + ci * 8] = pk.u4;
        }
    }
    // wave-private LDS rows: in-wave ds ordering, no barrier needed

    // ---- phase B: MFMA MLP ----
    int q4 = lane >> 4, c16 = lane & 15;
    int rowb = w * 16;
    const h8* WB1 = Wsw;            // frags [kt][nt][lane]
    const h8* WB2 = Wsw + 8 * 64;
    h8 A0 = *(const h8*)&sA[(size_t)(rowb + c16) * ASTRIDE + q4 * 8];
    h8 A1 = *(const h8*)&sA[(size_t)(rowb + c16) * ASTRIDE + 32 + q4 * 8];
    f32x4 C1[4];
#pragma unroll
    for (int nt = 0; nt < 4; nt++) {
        f32x4 c = {0.f, 0.f, 0.f, 0.f};
        c = __builtin_amdgcn_mfma_f32_16x16x32_f16(A0, WB1[nt * 64 + lane], c, 0, 0, 0);
        c = __builtin_amdgcn_mfma_f32_16x16x32_f16(A1, WB1[(4 + nt) * 64 + lane], c, 0, 0, 0);
        C1[nt] = c;
    }
#pragma unroll
    for (int nt = 0; nt < 4; nt++) {
        float bb = b1[nt * 16 + c16];
#pragma unroll
        for (int reg = 0; reg < 4; reg++) {
            float v = softplus_f(C1[nt][reg] + bb);
            sA[(size_t)(rowb + q4 * 4 + reg) * ASTRIDE + nt * 16 + c16] = (_Float16)v;
        }
    }
    h8 M0 = *(const h8*)&sA[(size_t)(rowb + c16) * ASTRIDE + q4 * 8];
    h8 M1 = *(const h8*)&sA[(size_t)(rowb + c16) * ASTRIDE + 32 + q4 * 8];
    f32x4 C2[4];
#pragma unroll
    for (int nt = 0; nt < 4; nt++) {
        f32x4 c = {0.f, 0.f, 0.f, 0.f};
        c = __builtin_amdgcn_mfma_f32_16x16x32_f16(M0, WB2[nt * 64 + lane], c, 0, 0, 0);
        c = __builtin_amdgcn_mfma_f32_16x16x32_f16(M1, WB2[(4 + nt) * 64 + lane], c, 0, 0, 0);
        C2[nt] = c;
    }
#pragma unroll
    for (int nt = 0; nt < 4; nt++) {
        float bb2 = b2p[nt * 16 + c16];
#pragma unroll
        for (int reg = 0; reg < 4; reg++) {
            int node = base + q4 * 4 + reg;
            if (node < N) {
                size_t idx = (size_t)node * H + nt * 16 + c16;
                float hn = __half2float(hb[idx]) + C2[nt][reg] + bb2;
                hb[idx] = __float2half(hn);
                __hip_fp8_e4m3 q(hn);
                hq_out[idx] = q.__x;
            }
        }
    }
}

// Stage 1 of mean: per-block partial sums to DISTINCT rows — no atomics.
__global__ __launch_bounds__(256)
void k_mean(const __half* __restrict__ hb, float* __restrict__ partials, int N) {
    __shared__ float s_r[4][H];
    int lane = threadIdx.x & 63;
    int w = threadIdx.x >> 6;
    int wg = blockIdx.x * 4 + w;
    int stride = gridDim.x * 4;
    float local = 0.f;
    for (int i = wg; i < N; i += stride) local += __half2float(hb[(size_t)i * H + lane]);
    s_r[w][lane] = local;
    __syncthreads();
    if (w == 0) {
        float s = s_r[0][lane] + s_r[1][lane] + s_r[2][lane] + s_r[3][lane];
        partials[(size_t)blockIdx.x * H + lane] = s;
    }
}

// Stage 2: one block reduces MEANB partial rows, then the tiny output MLP.
__global__ __launch_bounds__(256)
void k_final(const float* __restrict__ partials, int N,
             const float* __restrict__ oW1, const float* __restrict__ ob1,
             const float* __restrict__ og1, const float* __restrict__ obt1,
             const float* __restrict__ oW2, const float* __restrict__ ob2,
             const float* __restrict__ og2, const float* __restrict__ obt2,
             const float* __restrict__ fin_W, const float* __restrict__ fin_b,
             float* __restrict__ out) {
    __shared__ float red[4][H];
    __shared__ float sg[H], su[H / 2], sv[H / 2];
    int t = threadIdx.x;
    int ch = t & 63, grp = t >> 6;
    float s = 0.f;
    for (int b = grp; b < MEANB; b += 4) s += partials[(size_t)b * H + ch];
    red[grp][ch] = s;
    __syncthreads();
    if (t < H) sg[t] = (red[0][t] + red[1][t] + red[2][t] + red[3][t]) / (float)N;
    __syncthreads();
    int j = t;
    if (j < H / 2) {
        float acc = ob1[j];
        for (int k = 0; k < H; k++) acc += sg[k] * oW1[k * (H / 2) + j];
        su[j] = softplus_f(acc) * BN_INV * og1[j] + obt1[j];
    }
    __syncthreads();
    if (j < H / 2) {
        float acc = ob2[j];
        for (int k = 0; k < H / 2; k++) acc += su[k] * oW2[k * (H / 2) + j];
        sv[j] = softplus_f(acc) * BN_INV * og2[j] + obt2[j];
    }
    __syncthreads();
    if (j < 3) {
        float acc = fin_b[j];
        for (int k = 0; k < H / 2; k++) acc += sv[k] * fin_W[k * 3 + j];
        out[j] = acc;
    }
}

extern "C" void kernel_launch(void* const* d_in, const int* in_sizes, int n_in,
                              void* d_out, int out_size, void* d_ws, size_t ws_size,
                              hipStream_t stream) {
    const float* x      = (const float*)d_in[0];
    const int*   ei     = (const int*)d_in[1];
    const float* dist   = (const float*)d_in[2];
    /* d_in[3] edge_attr: unused by reference */
    const float* emb_W  = (const float*)d_in[4];
    const float* emb_b  = (const float*)d_in[5];
    const float* fW1    = (const float*)d_in[6];
    const float* fb1    = (const float*)d_in[7];
    const float* fW2    = (const float*)d_in[8];
    const float* fb2    = (const float*)d_in[9];
    const float* iW1    = (const float*)d_in[10];
    const float* ib1    = (const float*)d_in[11];
    const float* iW2    = (const float*)d_in[12];
    const float* ib2    = (const float*)d_in[13];
    const float* bn_g   = (const float*)d_in[14];
    const float* bn_b   = (const float*)d_in[15];
    const float* oW1    = (const float*)d_in[16];
    const float* ob1    = (const float*)d_in[17];
    const float* og1    = (const float*)d_in[18];
    const float* obt1   = (const float*)d_in[19];
    const float* oW2    = (const float*)d_in[20];
    const float* ob2    = (const float*)d_in[21];
    const float* og2    = (const float*)d_in[22];
    const float* obt2   = (const float*)d_in[23];
    const float* fin_W  = (const float*)d_in[24];
    const float* fin_b  = (const float*)d_in[25];
    float* out = (float*)d_out;

    int N = in_sizes[0] / FIN;
    int E = in_sizes[2];
    int nb_scan = (N + 255) / 256;

    // workspace layout (16B-aligned chunks first)
    float*  ws   = (float*)d_ws;
    __half* hb   = (__half*)ws;                            // N*H fp16 (in-place master)
    unsigned char* hq0 = (unsigned char*)(ws + (size_t)N * H / 2);   // N*H fp8
    unsigned char* hq1 = hq0 + (size_t)N * H;                        // N*H fp8
    unsigned int*  recs = (unsigned int*)(hq1 + (size_t)N * H);      // E uint32
    h8*     Wsw  = (h8*)(recs + E);                        // 3*2*8*64 h8
    float*  lut  = (float*)(Wsw + NLAYERS * 2 * 8 * 64);   // 3*LUTSTRIDE
    float*  partials = lut + 3 * LUTSTRIDE;                // MEANB*H
    float*  b2p  = partials + MEANB * H;                   // L*H
    int*    cnt8 = (int*)(b2p + NLAYERS * H);              // NPART*N
    int*    basep = cnt8 + (size_t)NPART * N;              // NPART*N
    int*    row_ptr = basep + (size_t)NPART * N;           // N+1
    int*    bsums   = row_ptr + (N + 1);                   // nb_scan (<=512)
    unsigned char* rank8 = (unsigned char*)(bsums + 512);  // E bytes

    int nbE = (N + 3) / 4;
    int nb_setup = nbE + NLAYERS * LUTB + 12;
    k_setup<<<nb_setup, 256, 0, stream>>>(x, emb_W, emb_b, hb, hq0,
                                          fW1, fb1, fW2, fb2, iW1, iW2,
                                          bn_g, bn_b, ib2, Wsw, b2p, lut,
                                          cnt8, N);

    int nb_edge = (E + 255) / 256;
    k_hist<<<nb_edge, 256, 0, stream>>>(ei, cnt8, rank8, N, E);
    k_scan1<<<nb_scan, 256, 0, stream>>>(cnt8, bsums, N);
    k_scan23<<<nb_scan, 256, 0, stream>>>(cnt8, bsums, row_ptr, basep, N, nb_scan);

    k_scatter<<<nb_edge, 256, 0, stream>>>(ei, dist, rank8, basep, recs, N, E);

    unsigned char* hqp[2] = {hq0, hq1};
    int nb_tile = (N + 63) / 64;
    for (int l = 0; l < NLAYERS; l++) {
        k_layer<<<nb_tile, 256, 0, stream>>>(row_ptr, recs, lut + (size_t)l * LUTSTRIDE,
                                             Wsw + (size_t)l * 1024,
                                             ib1 + l * H, b2p + l * H,
                                             hqp[l & 1], hqp[(l + 1) & 1], hb, N);
    }

    k_mean<<<MEANB, 256, 0, stream>>>(hb, partials, N);
    k_final<<<1, 256, 0, stream>>>(partials, N, oW1, ob1, og1, obt1,
                                   oW2, ob2, og2, obt2, fin_W, fin_b, out);
}

// Round 13
// 458.106 us; speedup vs baseline: 1.1415x; 1.0525x over previous
//
#include <hip/hip_runtime.h>
#include <hip/hip_fp16.h>
#include <math.h>

#define CUTOFF 5.0f
#define H 64
#define FIN 16
#define NLAYERS 3
#define LUTN 2048          // intervals; table has LUTN+1 entries
#define LUTSTRIDE 2052     // padded per-layer stride
#define ASTRIDE 72         // LDS row stride in halves (pad 64->72: <=2-way conflicts)
#define NPART 8            // histogram partitions (== XCD count)
#define MEANB 256          // blocks in mean pass (partials rows)
#define LUTB 9             // lut blocks per layer (9*256 >= 2049)

// 1/sqrt(1 + 1e-3)  (BN inference, moving mean 0 / var 1)
#define BN_INV 0.999500374750f

typedef _Float16 h8 __attribute__((ext_vector_type(8)));
typedef _Float16 h2 __attribute__((ext_vector_type(2)));
typedef float f32x4 __attribute__((ext_vector_type(4)));

__device__ __forceinline__ float softplus_f(float x) {
    return fmaxf(x, 0.f) + __logf(1.f + __expf(-fabsf(x)));
}

// ---- K1: mega setup. Block roles by blockIdx range:
//   [0, nbE)                 embed 4 nodes/block -> h0 fp16; zero 32 cnt8 ints
//   [nbE, nbE+27)            LUT: inline wsum/bsum in LDS, 256 entries/block
//   [nbE+27, nbE+39)         weight swizzle Wsw + b2p
__global__ __launch_bounds__(256)
void k_setup(const float* __restrict__ x, const float* __restrict__ emb_W,
             const float* __restrict__ emb_b, _Float16* __restrict__ h0,
             const float* __restrict__ fW1, const float* __restrict__ fb1,
             const float* __restrict__ fW2, const float* __restrict__ fb2,
             const float* __restrict__ iW1, const float* __restrict__ iW2,
             const float* __restrict__ bn_g, const float* __restrict__ bn_b,
             const float* __restrict__ ib2, h8* __restrict__ Wsw,
             float* __restrict__ b2p, float* __restrict__ lut,
             int* __restrict__ cnt8, int N) {
    __shared__ float swsum[64];
    __shared__ float sbsum;
    int b = blockIdx.x;
    int t = threadIdx.x;
    int nbE = (N + 3) / 4;
    if (b < nbE) {
        int ci = b * 32 + t;
        if (t < 32 && ci < NPART * N) cnt8[ci] = 0;
        int lane = t & 63;
        int w = t >> 6;
        int node = b * 4 + w;
        if (node < N) {
            float acc = emb_b[lane];
#pragma unroll
            for (int k = 0; k < FIN; k++) acc += x[node * FIN + k] * emb_W[k * H + lane];
            h0[(size_t)node * H + lane] = (_Float16)acc;
        }
    } else if (b < nbE + NLAYERS * LUTB) {
        int lb = b - nbE;
        int l = lb / LUTB, part = lb % LUTB;
        if (t < 64) {
            float s = 0.f;
            for (int j = 0; j < H; j++) s += fW2[l * H * H + t * H + j];
            swsum[t] = s;
        }
        if (t == 64) {
            float s = 0.f;
            for (int j = 0; j < H; j++) s += fb2[l * H + j];
            sbsum = s;
        }
        __syncthreads();
        int i = part * 256 + t;
        if (i <= LUTN) {
            float d = (float)i * (CUTOFF / (float)LUTN);
            float scaled = d * (2.0f / CUTOFF) - 1.0f;
            float cut = 0.5f * (__cosf(d * (3.14159265358979f / CUTOFF)) + 1.0f);
            if (d > CUTOFF) cut = 0.f;
            float s = 0.f;
            for (int hh = 0; hh < H; hh++) {
                int wi = l * H + hh;
                s += tanhf(scaled * fW1[wi] + fb1[wi]) * swsum[hh];
            }
            lut[l * LUTSTRIDE + i] = cut * (s + sbsum);
        }
    } else {
        int tid = (b - nbE - NLAYERS * LUTB) * 256 + t;
        if (tid < NLAYERS * H)
            b2p[tid] = ib2[tid] * BN_INV * bn_g[tid] + bn_b[tid];
        if (tid < NLAYERS * 2 * 8 * 64) {
            int lane = tid & 63;
            int frag = (tid >> 6) & 7;
            int mat  = (tid >> 9) & 1;
            int l    = tid >> 10;
            int kt = frag >> 2, nt = frag & 3;
            int n = nt * 16 + (lane & 15);
            int k0 = kt * 32 + (lane >> 4) * 8;
            const float* W = (mat ? iW2 : iW1) + l * H * H;
            float scale = mat ? BN_INV * bn_g[l * H + n] : 1.0f;
            h8 v;
#pragma unroll
            for (int j = 0; j < 8; j++) v[j] = (_Float16)(W[(k0 + j) * H + n] * scale);
            Wsw[tid] = v;
        }
    }
}

// Partitioned histogram: partition p = blockIdx%8. Atomic return value
// is the within-(partition,row) rank.
__global__ __launch_bounds__(256)
void k_hist(const int* __restrict__ ei, int* __restrict__ cnt8,
            unsigned char* __restrict__ rank8, int N, int E) {
    int e = blockIdx.x * 256 + threadIdx.x;
    if (e < E) {
        int p = blockIdx.x & (NPART - 1);
        int r = atomicAdd(&cnt8[(size_t)p * N + ei[e]], 1);
        rank8[e] = (unsigned char)r;
    }
}

// scan stage 1: per-256-row block sums of the row totals (8 partitions summed)
__global__ void k_scan1(const int* __restrict__ cnt8, int* __restrict__ bsums, int N) {
    __shared__ int sd[256];
    int i = blockIdx.x * 256 + threadIdx.x;
    int v = 0;
    if (i < N) {
#pragma unroll
        for (int p = 0; p < NPART; p++) v += cnt8[(size_t)p * N + i];
    }
    sd[threadIdx.x] = v;
    __syncthreads();
    for (int off = 128; off > 0; off >>= 1) {
        if (threadIdx.x < off) sd[threadIdx.x] += sd[threadIdx.x + off];
        __syncthreads();
    }
    if (threadIdx.x == 0) bsums[blockIdx.x] = sd[0];
}

// scan stage 2+3 fused: every block redundantly scans the <=512 block sums in
// LDS, takes its own base, then per-block scan of row totals -> row_ptr and
// per-partition bases base[p][row].
__global__ void k_scan23(const int* __restrict__ cnt8, const int* __restrict__ bsums,
                         int* __restrict__ row_ptr, int* __restrict__ base,
                         int N, int nb) {
    __shared__ int sd[256];
    __shared__ int ex[512];
    int t = threadIdx.x;
    int a0 = (2 * t     < nb) ? bsums[2 * t]     : 0;
    int a1 = (2 * t + 1 < nb) ? bsums[2 * t + 1] : 0;
    sd[t] = a0 + a1;
    __syncthreads();
    for (int off = 1; off < 256; off <<= 1) {
        int v = (t >= off) ? sd[t - off] : 0;
        __syncthreads();
        sd[t] += v;
        __syncthreads();
    }
    int pairExcl = (t == 0) ? 0 : sd[t - 1];
    ex[2 * t] = pairExcl;
    ex[2 * t + 1] = pairExcl + a0;
    __syncthreads();
    int myBase = ex[blockIdx.x];
    __syncthreads();

    int i = blockIdx.x * 256 + t;
    int c[NPART];
    int v = 0;
    if (i < N) {
#pragma unroll
        for (int p = 0; p < NPART; p++) { c[p] = cnt8[(size_t)p * N + i]; v += c[p]; }
    }
    sd[t] = v;
    __syncthreads();
    for (int off = 1; off < 256; off <<= 1) {
        int u = (t >= off) ? sd[t - off] : 0;
        __syncthreads();
        sd[t] += u;
        __syncthreads();
    }
    int excl = sd[t] - v + myBase;
    if (i < N) {
        row_ptr[i] = excl;
        int run = excl;
#pragma unroll
        for (int p = 0; p < NPART; p++) { base[(size_t)p * N + i] = run; run += c[p]; }
        if (i == N - 1) row_ptr[N] = excl + v;
    }
}

// Thread-per-edge, no atomics: pos = base[p][row] + rank8[e] (p matches k_hist).
// Pack {col:17b | d_quant:15b}; nontemporal store (avoid line allocate).
__global__ __launch_bounds__(256)
void k_scatter(const int* __restrict__ ei, const float* __restrict__ dist,
               const unsigned char* __restrict__ rank8, const int* __restrict__ base,
               unsigned int* __restrict__ recs, int N, int E) {
    int e = blockIdx.x * 256 + threadIdx.x;
    if (e >= E) return;
    int p = blockIdx.x & (NPART - 1);
    int row = ei[e], col = ei[E + e];
    float d = dist[e];
    int didx = (int)(d * (32768.0f / CUTOFF) + 0.5f);
    didx = max(0, min(didx, 32767));
    int pos = base[(size_t)p * N + row] + (int)rank8[e];
    __builtin_nontemporal_store(((unsigned)col << 15) | (unsigned)didx, &recs[pos]);
}

// Fused layer, packed-fp16 phase A. LDS LUT (fs lerped inline); 16 nodes/wave,
// 8 groups x 8 lanes, one uint4 (8 fp16 ch) gather per lane per edge,
// v_pk_fma_f16 accumulate (4 packed regs), packed butterfly; phase B: 64x64x2
// MLP as 16 MFMAs (fp16, BN folded in W2'). fp16 h double-buffered.
__global__ __launch_bounds__(256)
void k_layer(const int* __restrict__ row_ptr, const unsigned int* __restrict__ recs,
             const float* __restrict__ lutl, const h8* __restrict__ Wsw,
             const float* __restrict__ b1, const float* __restrict__ b2p,
             const _Float16* __restrict__ h_in, _Float16* __restrict__ h_out,
             int N) {
    __shared__ float s_lut[LUTN + 1];       // 8196 B
    __shared__ _Float16 sA[64 * ASTRIDE];   // 9216 B
    for (int i = threadIdx.x; i <= LUTN; i += 256) s_lut[i] = lutl[i];
    __syncthreads();

    int lane = threadIdx.x & 63;
    int w = threadIdx.x >> 6;
    int base = blockIdx.x * 64 + w * 16;    // this wave's 16 nodes
    int g = lane >> 3, ci = lane & 7;       // 8 groups x 8 lanes
    const uint4* h4 = (const uint4*)h_in;   // 8 halves per uint4; 8 per row

    // ---- phase A: aggregate (packed fp16) ----
    for (int i = 0; i < 16; i++) {
        int node = base + i;
        h2 acc[4];
#pragma unroll
        for (int q = 0; q < 4; q++) acc[q] = (h2){(_Float16)0.f, (_Float16)0.f};
        if (node < N) {
            int s = row_ptr[node], t = row_ptr[node + 1];
            for (int k = s + g; k < t; k += 8) {
                unsigned rec = recs[k];
                int c = rec >> 15;
                float td = (float)(rec & 32767u) * (1.0f / 16.0f);
                int i0 = (int)td;
                float fr = td - (float)i0;
                float f0 = s_lut[i0];
                float fv = f0 + fr * (s_lut[i0 + 1] - f0);
                _Float16 fvh = (_Float16)fv;
                h2 fv2 = (h2){fvh, fvh};
                union { uint4 u; h2 v[4]; } pk;
                pk.u = h4[(size_t)c * 8 + ci];
#pragma unroll
                for (int q = 0; q < 4; q++) acc[q] += fv2 * pk.v[q];
            }
        }
#pragma unroll
        for (int m = 8; m <= 32; m <<= 1) {
#pragma unroll
            for (int q = 0; q < 4; q++) {
                union { h2 v; int u; } a, b;
                a.v = acc[q];
                b.u = __shfl_xor(a.u, m, 64);
                acc[q] += b.v;
            }
        }
        if (g == 0) {
            union { uint4 u4; h2 v[4]; } pk;
#pragma unroll
            for (int q = 0; q < 4; q++) pk.v[q] = acc[q];
            *(uint4*)&sA[(size_t)(w * 16 + i) * ASTRIDE + ci * 8] = pk.u4;
        }
    }
    // wave-private LDS rows: in-wave ds ordering, no barrier needed

    // ---- phase B: MFMA MLP ----
    int q4 = lane >> 4, c16 = lane & 15;
    int rowb = w * 16;
    const h8* WB1 = Wsw;            // frags [kt][nt][lane]
    const h8* WB2 = Wsw + 8 * 64;
    h8 A0 = *(const h8*)&sA[(size_t)(rowb + c16) * ASTRIDE + q4 * 8];
    h8 A1 = *(const h8*)&sA[(size_t)(rowb + c16) * ASTRIDE + 32 + q4 * 8];
    f32x4 C1[4];
#pragma unroll
    for (int nt = 0; nt < 4; nt++) {
        f32x4 c = {0.f, 0.f, 0.f, 0.f};
        c = __builtin_amdgcn_mfma_f32_16x16x32_f16(A0, WB1[nt * 64 + lane], c, 0, 0, 0);
        c = __builtin_amdgcn_mfma_f32_16x16x32_f16(A1, WB1[(4 + nt) * 64 + lane], c, 0, 0, 0);
        C1[nt] = c;
    }
#pragma unroll
    for (int nt = 0; nt < 4; nt++) {
        float bb = b1[nt * 16 + c16];
#pragma unroll
        for (int reg = 0; reg < 4; reg++) {
            float v = softplus_f(C1[nt][reg] + bb);
            sA[(size_t)(rowb + q4 * 4 + reg) * ASTRIDE + nt * 16 + c16] = (_Float16)v;
        }
    }
    h8 M0 = *(const h8*)&sA[(size_t)(rowb + c16) * ASTRIDE + q4 * 8];
    h8 M1 = *(const h8*)&sA[(size_t)(rowb + c16) * ASTRIDE + 32 + q4 * 8];
    f32x4 C2[4];
#pragma unroll
    for (int nt = 0; nt < 4; nt++) {
        f32x4 c = {0.f, 0.f, 0.f, 0.f};
        c = __builtin_amdgcn_mfma_f32_16x16x32_f16(M0, WB2[nt * 64 + lane], c, 0, 0, 0);
        c = __builtin_amdgcn_mfma_f32_16x16x32_f16(M1, WB2[(4 + nt) * 64 + lane], c, 0, 0, 0);
        C2[nt] = c;
    }
    // epilogue: + b2' (BN folded), fp16 residual, dbuf write
#pragma unroll
    for (int nt = 0; nt < 4; nt++) {
        float bb2 = b2p[nt * 16 + c16];
#pragma unroll
        for (int reg = 0; reg < 4; reg++) {
            int node = base + q4 * 4 + reg;
            if (node < N) {
                size_t idx = (size_t)node * H + nt * 16 + c16;
                float hn = (float)h_in[idx] + C2[nt][reg] + bb2;
                h_out[idx] = (_Float16)hn;
            }
        }
    }
}

// Stage 1 of mean: per-block partial sums to DISTINCT rows — no atomics.
__global__ __launch_bounds__(256)
void k_mean(const _Float16* __restrict__ hb, float* __restrict__ partials, int N) {
    __shared__ float s_r[4][H];
    int lane = threadIdx.x & 63;
    int w = threadIdx.x >> 6;
    int wg = blockIdx.x * 4 + w;
    int stride = gridDim.x * 4;
    float local = 0.f;
    for (int i = wg; i < N; i += stride) local += (float)hb[(size_t)i * H + lane];
    s_r[w][lane] = local;
    __syncthreads();
    if (w == 0) {
        float s = s_r[0][lane] + s_r[1][lane] + s_r[2][lane] + s_r[3][lane];
        partials[(size_t)blockIdx.x * H + lane] = s;
    }
}

// Stage 2: one block reduces MEANB partial rows, then the tiny output MLP.
__global__ __launch_bounds__(256)
void k_final(const float* __restrict__ partials, int N,
             const float* __restrict__ oW1, const float* __restrict__ ob1,
             const float* __restrict__ og1, const float* __restrict__ obt1,
             const float* __restrict__ oW2, const float* __restrict__ ob2,
             const float* __restrict__ og2, const float* __restrict__ obt2,
             const float* __restrict__ fin_W, const float* __restrict__ fin_b,
             float* __restrict__ out) {
    __shared__ float red[4][H];
    __shared__ float sg[H], su[H / 2], sv[H / 2];
    int t = threadIdx.x;
    int ch = t & 63, grp = t >> 6;
    float s = 0.f;
    for (int b = grp; b < MEANB; b += 4) s += partials[(size_t)b * H + ch];
    red[grp][ch] = s;
    __syncthreads();
    if (t < H) sg[t] = (red[0][t] + red[1][t] + red[2][t] + red[3][t]) / (float)N;
    __syncthreads();
    int j = t;
    if (j < H / 2) {
        float acc = ob1[j];
        for (int k = 0; k < H; k++) acc += sg[k] * oW1[k * (H / 2) + j];
        su[j] = softplus_f(acc) * BN_INV * og1[j] + obt1[j];
    }
    __syncthreads();
    if (j < H / 2) {
        float acc = ob2[j];
        for (int k = 0; k < H / 2; k++) acc += su[k] * oW2[k * (H / 2) + j];
        sv[j] = softplus_f(acc) * BN_INV * og2[j] + obt2[j];
    }
    __syncthreads();
    if (j < 3) {
        float acc = fin_b[j];
        for (int k = 0; k < H / 2; k++) acc += sv[k] * fin_W[k * 3 + j];
        out[j] = acc;
    }
}

extern "C" void kernel_launch(void* const* d_in, const int* in_sizes, int n_in,
                              void* d_out, int out_size, void* d_ws, size_t ws_size,
                              hipStream_t stream) {
    const float* x      = (const float*)d_in[0];
    const int*   ei     = (const int*)d_in[1];
    const float* dist   = (const float*)d_in[2];
    /* d_in[3] edge_attr: unused by reference */
    const float* emb_W  = (const float*)d_in[4];
    const float* emb_b  = (const float*)d_in[5];
    const float* fW1    = (const float*)d_in[6];
    const float* fb1    = (const float*)d_in[7];
    const float* fW2    = (const float*)d_in[8];
    const float* fb2    = (const float*)d_in[9];
    const float* iW1    = (const float*)d_in[10];
    const float* ib1    = (const float*)d_in[11];
    const float* iW2    = (const float*)d_in[12];
    const float* ib2    = (const float*)d_in[13];
    const float* bn_g   = (const float*)d_in[14];
    const float* bn_b   = (const float*)d_in[15];
    const float* oW1    = (const float*)d_in[16];
    const float* ob1    = (const float*)d_in[17];
    const float* og1    = (const float*)d_in[18];
    const float* obt1   = (const float*)d_in[19];
    const float* oW2    = (const float*)d_in[20];
    const float* ob2    = (const float*)d_in[21];
    const float* og2    = (const float*)d_in[22];
    const float* obt2   = (const float*)d_in[23];
    const float* fin_W  = (const float*)d_in[24];
    const float* fin_b  = (const float*)d_in[25];
    float* out = (float*)d_out;

    int N = in_sizes[0] / FIN;
    int E = in_sizes[2];
    int nb_scan = (N + 255) / 256;

    // workspace layout (16B-aligned chunks first)
    float*  ws   = (float*)d_ws;
    _Float16* h0 = (_Float16*)ws;                          // N*H fp16
    _Float16* h1 = h0 + (size_t)N * H;                     // N*H fp16
    unsigned int*  recs = (unsigned int*)(h1 + (size_t)N * H);   // E uint32
    h8*     Wsw  = (h8*)(recs + E);                        // 3*2*8*64 h8
    float*  lut  = (float*)(Wsw + NLAYERS * 2 * 8 * 64);   // 3*LUTSTRIDE
    float*  partials = lut + 3 * LUTSTRIDE;                // MEANB*H
    float*  b2p  = partials + MEANB * H;                   // L*H
    int*    cnt8 = (int*)(b2p + NLAYERS * H);              // NPART*N
    int*    basep = cnt8 + (size_t)NPART * N;              // NPART*N
    int*    row_ptr = basep + (size_t)NPART * N;           // N+1
    int*    bsums   = row_ptr + (N + 1);                   // nb_scan (<=512)
    unsigned char* rank8 = (unsigned char*)(bsums + 512);  // E bytes

    int nbE = (N + 3) / 4;
    int nb_setup = nbE + NLAYERS * LUTB + 12;
    k_setup<<<nb_setup, 256, 0, stream>>>(x, emb_W, emb_b, h0,
                                          fW1, fb1, fW2, fb2, iW1, iW2,
                                          bn_g, bn_b, ib2, Wsw, b2p, lut,
                                          cnt8, N);

    int nb_edge = (E + 255) / 256;
    k_hist<<<nb_edge, 256, 0, stream>>>(ei, cnt8, rank8, N, E);
    k_scan1<<<nb_scan, 256, 0, stream>>>(cnt8, bsums, N);
    k_scan23<<<nb_scan, 256, 0, stream>>>(cnt8, bsums, row_ptr, basep, N, nb_scan);

    k_scatter<<<nb_edge, 256, 0, stream>>>(ei, dist, rank8, basep, recs, N, E);

    _Float16* hp[2] = {h0, h1};
    int nb_tile = (N + 63) / 64;
    for (int l = 0; l < NLAYERS; l++) {
        k_layer<<<nb_tile, 256, 0, stream>>>(row_ptr, recs, lut + (size_t)l * LUTSTRIDE,
                                             Wsw + (size_t)l * 1024,
                                             ib1 + l * H, b2p + l * H,
                                             hp[l & 1], hp[(l + 1) & 1], N);
    }
    _Float16* h_final = hp[NLAYERS & 1];

    k_mean<<<MEANB, 256, 0, stream>>>(h_final, partials, N);
    k_final<<<1, 256, 0, stream>>>(partials, N, oW1, ob1, og1, obt1,
                                   oW2, ob2, og2, obt2, fin_W, fin_b, out);
}